// Round 5
// baseline (821.735 us; speedup 1.0000x reference)
//
#include <hip/hip_runtime.h>

#define N_NODES 100000
#define E_EDGES 3200000
#define SCAN_BLOCKS 98
#define SCAN_CHUNK 1024  // 98*1024 = 100352 >= N_NODES

// ---------------------------------------------------------------------------
// ws layout (float offsets):
//   hem    [0,        6400000)    N*64   h_em = x @ emb_w + emb_b
//   s8     [6400000,  7200000)    N*8    [s_src+att_b (4) | s_dst (4)] per node
//   Wa_t   [7200000,  7202048)    8*256  transposed fused [a_src|a_dst] @ W_lin^T
//   off8   [7202048,  7202056)    8      b_lin . a^T
//   counts [7202056,  7302056)    N ints (zeroed by scan3, reused as fill)
//   rowptr [7302056,  7402057)    N+1 ints
//   bsum   [7402064,  7402192)    128 ints (scan partials)
//   boff   [7402192,  7402320)    128 ints (scan block offsets)
//   sdst   [7502064, 10702064)    E ints (dst sorted by src)
// ---------------------------------------------------------------------------

__global__ void fuse_weights_kernel(const float* __restrict__ W_lin,
                                    const float* __restrict__ b_lin,
                                    const float* __restrict__ att_w,
                                    float* __restrict__ Wa_t,
                                    float* __restrict__ off8) {
    int k = threadIdx.x;  // 0..255, one row of W_lin
    float acc[8];
#pragma unroll
    for (int j = 0; j < 8; ++j) acc[j] = 0.f;
    for (int c = 0; c < 256; ++c) {
        float w = W_lin[k * 256 + c];
#pragma unroll
        for (int l = 0; l < 4; ++l) {
            acc[l]     += w * att_w[l * 512 + c];        // a_src[l][c]
            acc[4 + l] += w * att_w[l * 512 + 256 + c];  // a_dst[l][c]
        }
    }
#pragma unroll
    for (int j = 0; j < 8; ++j) Wa_t[j * 256 + k] = acc[j];  // transposed
    if (k < 8) {
        int l = k & 3, part = k >> 2;
        float o = 0.f;
        for (int c = 0; c < 256; ++c)
            o += b_lin[c] * att_w[l * 512 + part * 256 + c];
        off8[k] = o;
    }
}

// 8 rows per wave, no LDS, no shuffles.
//  hem: lane owns output column `lane`; x rows come in as wave-uniform
//       broadcast float4 loads (8KB working set, L1-hot); emb_w coalesced.
//  s8:  lane = (row = lane>>3, j = lane&7) computes one full 256-dot
//       against Wa_t[j][:]; store is one coalesced 64-lane write.
__global__ __launch_bounds__(256) void row_kernel(
    const float* __restrict__ x,
    const float* __restrict__ emb_w, const float* __restrict__ emb_b,
    const float* __restrict__ Wa_t, const float* __restrict__ off8,
    const float* __restrict__ att_b,
    float* __restrict__ hem, float* __restrict__ s8) {
    const int wave = threadIdx.x >> 6, lane = threadIdx.x & 63;
    const int g = blockIdx.x * 4 + wave;  // 12500 groups of 8 rows, exact
    if (g >= N_NODES / 8) return;
    const int row0 = g * 8;

    // ---- h_em for 8 rows ----
    const float eb = emb_b[lane];
    float acc[8];
#pragma unroll
    for (int r = 0; r < 8; ++r) acc[r] = eb;
    for (int k4 = 0; k4 < 64; ++k4) {
        const float* ew = emb_w + k4 * 256 + lane;
        float w0 = ew[0], w1 = ew[64], w2 = ew[128], w3 = ew[192];
#pragma unroll
        for (int r = 0; r < 8; ++r) {
            float4 xv = *(const float4*)(x + (size_t)(row0 + r) * 256 + k4 * 4);
            acc[r] += xv.x * w0 + xv.y * w1 + xv.z * w2 + xv.w * w3;
        }
    }
#pragma unroll
    for (int r = 0; r < 8; ++r)
        hem[(size_t)(row0 + r) * 64 + lane] = acc[r];

    // ---- s8 for 8 rows: one dot product per lane ----
    const int r = lane >> 3, j = lane & 7;
    const float* xr = x + (size_t)(row0 + r) * 256;  // L1-hot from hem loop
    const float* wj = Wa_t + j * 256;                // 8KB, L1-resident
    float s = 0.f;
    for (int k4 = 0; k4 < 64; ++k4) {
        float4 xv = *(const float4*)(xr + k4 * 4);
        float4 wv = *(const float4*)(wj + k4 * 4);
        s += xv.x * wv.x + xv.y * wv.y + xv.z * wv.z + xv.w * wv.w;
    }
    s += off8[j] + (j < 4 ? att_b[j] : 0.f);
    s8[(size_t)row0 * 8 + lane] = s;  // 64 consecutive floats, coalesced
}

// One thread per edge: depth-1 latency chains, wave turnover hides atomics.
__global__ __launch_bounds__(256) void hist_kernel(const int* __restrict__ src,
                                                   int* __restrict__ counts) {
    int e = blockIdx.x * 256 + threadIdx.x;
    if (e < E_EDGES) atomicAdd(&counts[src[e]], 1);
}

// -------- three-kernel parallel exclusive scan over counts -> rowptr -------
__global__ __launch_bounds__(256) void scan1_kernel(const int* __restrict__ counts,
                                                    int* __restrict__ bsum) {
    __shared__ int red[256];
    const int b = blockIdx.x, t = threadIdx.x;
    const int base = b * SCAN_CHUNK;
    int s = 0;
    for (int i = t; i < SCAN_CHUNK; i += 256) {
        int idx = base + i;
        s += (idx < N_NODES) ? counts[idx] : 0;
    }
    red[t] = s;
    __syncthreads();
    for (int off = 128; off >= 1; off >>= 1) {
        if (t < off) red[t] += red[t + off];
        __syncthreads();
    }
    if (t == 0) bsum[b] = red[0];
}

__global__ __launch_bounds__(128) void scan2_kernel(const int* __restrict__ bsum,
                                                    int* __restrict__ boff,
                                                    int* __restrict__ rowptr) {
    __shared__ int sh[128];
    const int t = threadIdx.x;
    sh[t] = (t < SCAN_BLOCKS) ? bsum[t] : 0;
    __syncthreads();
    for (int off = 1; off < 128; off <<= 1) {
        int v = (t >= off) ? sh[t - off] : 0;
        __syncthreads();
        sh[t] += v;
        __syncthreads();
    }
    if (t < SCAN_BLOCKS) boff[t] = (t == 0) ? 0 : sh[t - 1];
    if (t == 0) rowptr[N_NODES] = E_EDGES;
}

__global__ __launch_bounds__(256) void scan3_kernel(int* __restrict__ counts,
                                                    const int* __restrict__ boff,
                                                    int* __restrict__ rowptr) {
    __shared__ int sh[256];
    const int b = blockIdx.x, t = threadIdx.x;
    const int base = b * SCAN_CHUNK;
    int running = boff[b];
    for (int tile = 0; tile < SCAN_CHUNK; tile += 256) {
        const int idx = base + tile + t;
        const int v = (idx < N_NODES) ? counts[idx] : 0;
        sh[t] = v;
        __syncthreads();
        for (int off = 1; off < 256; off <<= 1) {  // inclusive Hillis-Steele
            int u = (t >= off) ? sh[t - off] : 0;
            __syncthreads();
            sh[t] += u;
            __syncthreads();
        }
        if (idx < N_NODES) {
            rowptr[idx] = running + sh[t] - v;  // exclusive
            counts[idx] = 0;                    // becomes fill[] for scatter
        }
        running += sh[255];
        __syncthreads();  // protect sh[255] before next tile overwrites
    }
}
// ---------------------------------------------------------------------------

// One thread per edge: load src -> atomic -> one random store, depth-1 chain.
__global__ __launch_bounds__(256) void scatter_kernel(
    const int* __restrict__ src, const int* __restrict__ dst,
    const int* __restrict__ rowptr, int* __restrict__ fill,
    int* __restrict__ sdst) {
    int e = blockIdx.x * 256 + threadIdx.x;
    if (e < E_EDGES) {
        int s = src[e];
        int pos = rowptr[s] + atomicAdd(&fill[s], 1);
        sdst[pos] = dst[e];
    }
}

// One wave per src node. Phase 1: each lane computes the 4 edge-weights for
// ONE edge of the batch -> LDS. Phase 2: broadcast weights, gather hem rows.
__global__ __launch_bounds__(256) void node_kernel(
    const int* __restrict__ rowptr, const int* __restrict__ sdst,
    const float* __restrict__ s8, const float* __restrict__ hem,
    float* __restrict__ out) {
    __shared__ int    wd[4][64];
    __shared__ float4 ww[4][64];
    const int wave = threadIdx.x >> 6, lane = threadIdx.x & 63;
    const int gw = (blockIdx.x * blockDim.x + threadIdx.x) >> 6;
    const int nw = (gridDim.x * blockDim.x) >> 6;
    for (int s = gw; s < N_NODES; s += nw) {
        const int beg = rowptr[s], end = rowptr[s + 1];
        const float4 ssv = *(const float4*)(s8 + (size_t)s * 8);  // +att_b
        float a0 = 0.f, a1 = 0.f, a2 = 0.f, a3 = 0.f;
        float d0 = 0.f, d1 = 0.f, d2 = 0.f, d3 = 0.f;
        for (int base = beg; base < end; base += 64) {
            const int m = min(64, end - base);
            if (lane < m) {
                int dj = sdst[base + lane];
                float4 sd = *(const float4*)(s8 + (size_t)dj * 8 + 4);
                float w0 = __expf(1.f / (1.f + __expf(-(ssv.x + sd.x))));
                float w1 = __expf(1.f / (1.f + __expf(-(ssv.y + sd.y))));
                float w2 = __expf(1.f / (1.f + __expf(-(ssv.z + sd.z))));
                float w3 = __expf(1.f / (1.f + __expf(-(ssv.w + sd.w))));
                wd[wave][lane] = dj;
                ww[wave][lane] = make_float4(w0, w1, w2, w3);
            }
            // producer == consumer wave: DS ops in-order, no block barrier
            int j = 0;
            for (; j + 1 < m; j += 2) {
                int da = wd[wave][j], db = wd[wave][j + 1];
                float4 wa = ww[wave][j], wb = ww[wave][j + 1];
                float ha = hem[(size_t)da * 64 + lane];
                float hb = hem[(size_t)db * 64 + lane];
                a0 += wa.x * ha; a1 += wa.y * ha; a2 += wa.z * ha; a3 += wa.w * ha;
                d0 += wa.x + wb.x; d1 += wa.y + wb.y;
                d2 += wa.z + wb.z; d3 += wa.w + wb.w;
                a0 += wb.x * hb; a1 += wb.y * hb; a2 += wb.z * hb; a3 += wb.w * hb;
            }
            if (j < m) {
                int da = wd[wave][j];
                float4 wa = ww[wave][j];
                float ha = hem[(size_t)da * 64 + lane];
                a0 += wa.x * ha; a1 += wa.y * ha; a2 += wa.z * ha; a3 += wa.w * ha;
                d0 += wa.x; d1 += wa.y; d2 += wa.z; d3 += wa.w;
            }
        }
        float* o = out + (size_t)s * 256;
        o[lane]       = d0 > 0.f ? a0 / d0 : 0.f;
        o[64 + lane]  = d1 > 0.f ? a1 / d1 : 0.f;
        o[128 + lane] = d2 > 0.f ? a2 / d2 : 0.f;
        o[192 + lane] = d3 > 0.f ? a3 / d3 : 0.f;
    }
}

extern "C" void kernel_launch(void* const* d_in, const int* in_sizes, int n_in,
                              void* d_out, int out_size, void* d_ws, size_t ws_size,
                              hipStream_t stream) {
    const float* x     = (const float*)d_in[0];
    const int*   src   = (const int*)d_in[1];
    const int*   dst   = (const int*)d_in[2];
    const float* W_lin = (const float*)d_in[3];
    const float* b_lin = (const float*)d_in[4];
    const float* att_w = (const float*)d_in[5];
    const float* att_b = (const float*)d_in[6];
    const float* emb_w = (const float*)d_in[7];
    const float* emb_b = (const float*)d_in[8];
    float* out = (float*)d_out;
    float* ws  = (float*)d_ws;

    float* hem    = ws;
    float* s8     = ws + 6400000;
    float* Wa_t   = ws + 7200000;
    float* off8   = ws + 7202048;
    int*   counts = (int*)(ws + 7202056);
    int*   rowptr = (int*)(ws + 7302056);
    int*   bsum   = (int*)(ws + 7402064);
    int*   boff   = (int*)(ws + 7402192);
    int*   sdst   = (int*)(ws + 7502064);

    hipMemsetAsync(counts, 0, N_NODES * sizeof(int), stream);

    fuse_weights_kernel<<<1, 256, 0, stream>>>(W_lin, b_lin, att_w, Wa_t, off8);
    row_kernel<<<3125, 256, 0, stream>>>(x, emb_w, emb_b, Wa_t, off8, att_b,
                                         hem, s8);
    hist_kernel<<<(E_EDGES + 255) / 256, 256, 0, stream>>>(src, counts);
    scan1_kernel<<<SCAN_BLOCKS, 256, 0, stream>>>(counts, bsum);
    scan2_kernel<<<1, 128, 0, stream>>>(bsum, boff, rowptr);
    scan3_kernel<<<SCAN_BLOCKS, 256, 0, stream>>>(counts, boff, rowptr);
    scatter_kernel<<<(E_EDGES + 255) / 256, 256, 0, stream>>>(src, dst, rowptr,
                                                              counts, sdst);
    node_kernel<<<4096, 256, 0, stream>>>(rowptr, sdst, s8, hem, out);
}

// Round 6
// 557.628 us; speedup vs baseline: 1.4736x; 1.4736x over previous
//
#include <hip/hip_runtime.h>

#define N_NODES 100000
#define E_EDGES 3200000
#define SCAN_BLOCKS 98
#define SCAN_CHUNK 1024  // 98*1024 = 100352 >= N_NODES

// Wct: transposed fused weight matrix, bf16, [80 cols][264 k-stride]
//   cols 0..63  = emb_w^T, cols 64..71 = (W_lin @ [a_src|a_dst]^T)^T,
//   cols 72..79 = unused (never stored from), k-pad 256..263 never read.
#define WCT_STRIDE 264
#define WCT_ELEMS (80 * WCT_STRIDE)  // 21120 ushorts = 42240 B

// ---------------------------------------------------------------------------
// ws layout (float offsets):
//   hem_bf [0,        3200000)    N*64 ushort (bf16 h_em)
//   s8     [3200000,  4000000)    N*8 f32  [s_src+att_b (4) | s_dst (4)]
//   Wct    [4000000,  4010560)    21120 ushort (see above)
//   off8   [4010560,  4010568)    8 f32   b_lin . a^T
//   counts [4010568,  4110568)    N ints (zeroed by scan3, reused as fill)
//   rowptr [4110568,  4210569)    N+1 ints
//   bsum   [4210576,  4210704)    128 ints
//   boff   [4210704,  4210832)    128 ints
//   sdst   [4210832,  7410832)    E ints (dst sorted by src)
// ---------------------------------------------------------------------------

typedef __attribute__((ext_vector_type(8))) short short8;
typedef __attribute__((ext_vector_type(4))) float f32x4;

__device__ __forceinline__ unsigned short f2bf(float f) {
    unsigned u = __float_as_uint(f);
    return (unsigned short)((u + 0x7FFFu + ((u >> 16) & 1u)) >> 16);  // RNE
}

__device__ __forceinline__ float rdlf(float v, int l) {
    return __int_as_float(__builtin_amdgcn_readlane(__float_as_int(v), l));
}

__global__ void fuse_weights_kernel(const float* __restrict__ W_lin,
                                    const float* __restrict__ b_lin,
                                    const float* __restrict__ att_w,
                                    const float* __restrict__ emb_w,
                                    unsigned short* __restrict__ Wct,
                                    float* __restrict__ off8) {
    int k = threadIdx.x;  // 0..255, one row of W_lin / one k of Wct
    float acc[8];
#pragma unroll
    for (int j = 0; j < 8; ++j) acc[j] = 0.f;
    for (int c = 0; c < 256; ++c) {
        float w = W_lin[k * 256 + c];
#pragma unroll
        for (int l = 0; l < 4; ++l) {
            acc[l]     += w * att_w[l * 512 + c];        // a_src[l][c]
            acc[4 + l] += w * att_w[l * 512 + 256 + c];  // a_dst[l][c]
        }
    }
    for (int c = 0; c < 64; ++c)
        Wct[c * WCT_STRIDE + k] = f2bf(emb_w[k * 64 + c]);
#pragma unroll
    for (int j = 0; j < 8; ++j)
        Wct[(64 + j) * WCT_STRIDE + k] = f2bf(acc[j]);
#pragma unroll
    for (int t = 0; t < 8; ++t)
        Wct[(72 + t) * WCT_STRIDE + k] = 0;  // unused cols, keep clean
    if (k < 8) {
        int l = k & 3, part = k >> 2;
        float o = 0.f;
        for (int c = 0; c < 256; ++c)
            o += b_lin[c] * att_w[l * 512 + part * 256 + c];
        off8[k] = o;
    }
}

// MFMA row kernel: one wave per 16-row tile, [hem | s8] = X @ Wct^T.
// A-frag: lane (g=lane>>4, r=lane&15) holds x[row0+r][kk*32 + g*8 + 0..7];
// B-frag: lane holds Wct[col=16n+r][kk*32 + g*8 + 0..7] (same k-map -> any
// k-permutation error cancels). C/D: col=lane&15, row=(lane>>4)*4+reg (m89).
__global__ __launch_bounds__(256) void row_mfma_kernel(
    const float* __restrict__ x, const unsigned short* __restrict__ Wct,
    const float* __restrict__ off8, const float* __restrict__ att_b,
    const float* __restrict__ emb_b,
    unsigned short* __restrict__ hem, float* __restrict__ s8) {
    __shared__ unsigned short Wl[WCT_ELEMS];  // 42240 B, stride-264 (2-way, free)
    const int tid = threadIdx.x;
    for (int i = tid; i < WCT_ELEMS / 8; i += 256)
        ((uint4*)Wl)[i] = ((const uint4*)Wct)[i];
    __syncthreads();
    const int wave = tid >> 6, lane = tid & 63;
    const int tile = blockIdx.x * 4 + wave;  // 6250 tiles of 16 rows (exact)
    if (tile >= N_NODES / 16) return;
    const int row0 = tile * 16;
    const int r = lane & 15, g = lane >> 4;
    const float* xr = x + (size_t)(row0 + r) * 256 + g * 8;

    f32x4 acc[5];
#pragma unroll
    for (int n = 0; n < 5; ++n) acc[n] = (f32x4){0.f, 0.f, 0.f, 0.f};

    for (int kk = 0; kk < 8; ++kk) {
        float4 xa = *(const float4*)(xr + kk * 32);
        float4 xb = *(const float4*)(xr + kk * 32 + 4);
        short8 a;
        a[0] = (short)f2bf(xa.x); a[1] = (short)f2bf(xa.y);
        a[2] = (short)f2bf(xa.z); a[3] = (short)f2bf(xa.w);
        a[4] = (short)f2bf(xb.x); a[5] = (short)f2bf(xb.y);
        a[6] = (short)f2bf(xb.z); a[7] = (short)f2bf(xb.w);
        const int bk = kk * 32 + g * 8;
#pragma unroll
        for (int n = 0; n < 5; ++n) {
            short8 b = *(const short8*)(&Wl[(16 * n + r) * WCT_STRIDE + bk]);
            acc[n] = __builtin_amdgcn_mfma_f32_16x16x32_bf16(a, b, acc[n], 0, 0, 0);
        }
    }
#pragma unroll
    for (int q = 0; q < 4; ++q) {
        const int orow = row0 + g * 4 + q;
#pragma unroll
        for (int n = 0; n < 4; ++n)
            hem[(size_t)orow * 64 + 16 * n + r] =
                f2bf(acc[n][q] + emb_b[16 * n + r]);
        if (r < 8)
            s8[(size_t)orow * 8 + r] =
                acc[4][q] + off8[r] + (r < 4 ? att_b[r] : 0.f);
    }
}

__global__ __launch_bounds__(256) void hist_kernel(const int* __restrict__ src,
                                                   int* __restrict__ counts) {
    int e = blockIdx.x * 256 + threadIdx.x;
    if (e < E_EDGES) atomicAdd(&counts[src[e]], 1);
}

// -------- three-kernel parallel exclusive scan over counts -> rowptr -------
__global__ __launch_bounds__(256) void scan1_kernel(const int* __restrict__ counts,
                                                    int* __restrict__ bsum) {
    __shared__ int red[256];
    const int b = blockIdx.x, t = threadIdx.x;
    const int base = b * SCAN_CHUNK;
    int s = 0;
    for (int i = t; i < SCAN_CHUNK; i += 256) {
        int idx = base + i;
        s += (idx < N_NODES) ? counts[idx] : 0;
    }
    red[t] = s;
    __syncthreads();
    for (int off = 128; off >= 1; off >>= 1) {
        if (t < off) red[t] += red[t + off];
        __syncthreads();
    }
    if (t == 0) bsum[b] = red[0];
}

__global__ __launch_bounds__(128) void scan2_kernel(const int* __restrict__ bsum,
                                                    int* __restrict__ boff,
                                                    int* __restrict__ rowptr) {
    __shared__ int sh[128];
    const int t = threadIdx.x;
    sh[t] = (t < SCAN_BLOCKS) ? bsum[t] : 0;
    __syncthreads();
    for (int off = 1; off < 128; off <<= 1) {
        int v = (t >= off) ? sh[t - off] : 0;
        __syncthreads();
        sh[t] += v;
        __syncthreads();
    }
    if (t < SCAN_BLOCKS) boff[t] = (t == 0) ? 0 : sh[t - 1];
    if (t == 0) rowptr[N_NODES] = E_EDGES;
}

__global__ __launch_bounds__(256) void scan3_kernel(int* __restrict__ counts,
                                                    const int* __restrict__ boff,
                                                    int* __restrict__ rowptr) {
    __shared__ int sh[256];
    const int b = blockIdx.x, t = threadIdx.x;
    const int base = b * SCAN_CHUNK;
    int running = boff[b];
    for (int tile = 0; tile < SCAN_CHUNK; tile += 256) {
        const int idx = base + tile + t;
        const int v = (idx < N_NODES) ? counts[idx] : 0;
        sh[t] = v;
        __syncthreads();
        for (int off = 1; off < 256; off <<= 1) {  // inclusive Hillis-Steele
            int u = (t >= off) ? sh[t - off] : 0;
            __syncthreads();
            sh[t] += u;
            __syncthreads();
        }
        if (idx < N_NODES) {
            rowptr[idx] = running + sh[t] - v;  // exclusive
            counts[idx] = 0;                    // becomes fill[] for scatter
        }
        running += sh[255];
        __syncthreads();
    }
}
// ---------------------------------------------------------------------------

__global__ __launch_bounds__(256) void scatter_kernel(
    const int* __restrict__ src, const int* __restrict__ dst,
    const int* __restrict__ rowptr, int* __restrict__ fill,
    int* __restrict__ sdst) {
    int e = blockIdx.x * 256 + threadIdx.x;
    if (e < E_EDGES) {
        int s = src[e];
        int pos = rowptr[s] + atomicAdd(&fill[s], 1);
        sdst[pos] = dst[e];
    }
}

// One wave per src node. Phase 1: lane j computes edge j's weights (regs).
// Phase 2: broadcast via v_readlane (VALU pipe, no LDS); denominators
// accumulate redundantly per-lane so no reduction is needed.
__global__ __launch_bounds__(256) void node_kernel(
    const int* __restrict__ rowptr, const int* __restrict__ sdst,
    const float* __restrict__ s8, const unsigned short* __restrict__ hem,
    float* __restrict__ out) {
    const int lane = threadIdx.x & 63;
    const int gw = (blockIdx.x * blockDim.x + threadIdx.x) >> 6;
    const int nw = (gridDim.x * blockDim.x) >> 6;
    for (int s = gw; s < N_NODES; s += nw) {
        const int beg = rowptr[s], end = rowptr[s + 1];
        const float4 ssv = *(const float4*)(s8 + (size_t)s * 8);  // +att_b
        float a0 = 0.f, a1 = 0.f, a2 = 0.f, a3 = 0.f;
        float d0 = 0.f, d1 = 0.f, d2 = 0.f, d3 = 0.f;
        for (int base = beg; base < end; base += 64) {
            const int m = min(64, end - base);
            int dj = 0;
            float w0 = 0.f, w1 = 0.f, w2 = 0.f, w3 = 0.f;
            if (lane < m) {
                dj = sdst[base + lane];
                float4 sd = *(const float4*)(s8 + (size_t)dj * 8 + 4);
                w0 = __expf(1.f / (1.f + __expf(-(ssv.x + sd.x))));
                w1 = __expf(1.f / (1.f + __expf(-(ssv.y + sd.y))));
                w2 = __expf(1.f / (1.f + __expf(-(ssv.z + sd.z))));
                w3 = __expf(1.f / (1.f + __expf(-(ssv.w + sd.w))));
            }
            int j = 0;
            for (; j + 1 < m; j += 2) {  // unroll-2: two independent gathers
                const int ra = __builtin_amdgcn_readlane(dj, j);
                const int rb = __builtin_amdgcn_readlane(dj, j + 1);
                const float va0 = rdlf(w0, j), va1 = rdlf(w1, j);
                const float va2 = rdlf(w2, j), va3 = rdlf(w3, j);
                const float vb0 = rdlf(w0, j + 1), vb1 = rdlf(w1, j + 1);
                const float vb2 = rdlf(w2, j + 1), vb3 = rdlf(w3, j + 1);
                const float ha = __uint_as_float(
                    (unsigned)hem[(size_t)ra * 64 + lane] << 16);
                const float hb = __uint_as_float(
                    (unsigned)hem[(size_t)rb * 64 + lane] << 16);
                a0 += va0 * ha; a1 += va1 * ha; a2 += va2 * ha; a3 += va3 * ha;
                d0 += va0 + vb0; d1 += va1 + vb1;
                d2 += va2 + vb2; d3 += va3 + vb3;
                a0 += vb0 * hb; a1 += vb1 * hb; a2 += vb2 * hb; a3 += vb3 * hb;
            }
            if (j < m) {
                const int ra = __builtin_amdgcn_readlane(dj, j);
                const float v0 = rdlf(w0, j), v1 = rdlf(w1, j);
                const float v2 = rdlf(w2, j), v3 = rdlf(w3, j);
                const float ha = __uint_as_float(
                    (unsigned)hem[(size_t)ra * 64 + lane] << 16);
                a0 += v0 * ha; a1 += v1 * ha; a2 += v2 * ha; a3 += v3 * ha;
                d0 += v0; d1 += v1; d2 += v2; d3 += v3;
            }
        }
        float* o = out + (size_t)s * 256;
        o[lane]       = d0 > 0.f ? a0 / d0 : 0.f;
        o[64 + lane]  = d1 > 0.f ? a1 / d1 : 0.f;
        o[128 + lane] = d2 > 0.f ? a2 / d2 : 0.f;
        o[192 + lane] = d3 > 0.f ? a3 / d3 : 0.f;
    }
}

extern "C" void kernel_launch(void* const* d_in, const int* in_sizes, int n_in,
                              void* d_out, int out_size, void* d_ws, size_t ws_size,
                              hipStream_t stream) {
    const float* x     = (const float*)d_in[0];
    const int*   src   = (const int*)d_in[1];
    const int*   dst   = (const int*)d_in[2];
    const float* W_lin = (const float*)d_in[3];
    const float* b_lin = (const float*)d_in[4];
    const float* att_w = (const float*)d_in[5];
    const float* att_b = (const float*)d_in[6];
    const float* emb_w = (const float*)d_in[7];
    const float* emb_b = (const float*)d_in[8];
    float* out = (float*)d_out;
    float* ws  = (float*)d_ws;

    unsigned short* hem = (unsigned short*)ws;
    float* s8     = ws + 3200000;
    unsigned short* Wct = (unsigned short*)(ws + 4000000);
    float* off8   = ws + 4010560;
    int*   counts = (int*)(ws + 4010568);
    int*   rowptr = (int*)(ws + 4110568);
    int*   bsum   = (int*)(ws + 4210576);
    int*   boff   = (int*)(ws + 4210704);
    int*   sdst   = (int*)(ws + 4210832);

    hipMemsetAsync(counts, 0, N_NODES * sizeof(int), stream);

    fuse_weights_kernel<<<1, 256, 0, stream>>>(W_lin, b_lin, att_w, emb_w,
                                               Wct, off8);
    row_mfma_kernel<<<1563, 256, 0, stream>>>(x, Wct, off8, att_b, emb_b,
                                              hem, s8);
    hist_kernel<<<(E_EDGES + 255) / 256, 256, 0, stream>>>(src, counts);
    scan1_kernel<<<SCAN_BLOCKS, 256, 0, stream>>>(counts, bsum);
    scan2_kernel<<<1, 128, 0, stream>>>(bsum, boff, rowptr);
    scan3_kernel<<<SCAN_BLOCKS, 256, 0, stream>>>(counts, boff, rowptr);
    scatter_kernel<<<(E_EDGES + 255) / 256, 256, 0, stream>>>(src, dst, rowptr,
                                                              counts, sdst);
    node_kernel<<<4096, 256, 0, stream>>>(rowptr, sdst, s8, hem, out);
}

// Round 7
// 319.588 us; speedup vs baseline: 2.5712x; 1.7448x over previous
//
#include <hip/hip_runtime.h>

#define N_NODES 100000
#define E_EDGES 3200000

// ---- bucket sort geometry ----
#define BSHIFT 7
#define BWIDTH 128                       // src values per bucket
#define NBUCKETS 782                     // ceil(100000/128)
#define NB1 200                          // partition blocks
#define CHUNK1 16000                     // NB1*CHUNK1 == E_EDGES exactly
#define SCAN_LEN (NBUCKETS * NB1)        // 156400
#define SCAN_CHUNK 1024
#define SCAN_BLOCKS 153                  // ceil(156400/1024)

// Wct: transposed fused weight matrix, bf16, [80 cols][264 k-stride]
#define WCT_STRIDE 264
#define WCT_ELEMS (80 * WCT_STRIDE)      // 21120 ushorts

// ---------------------------------------------------------------------------
// ws layout (int/float offsets):
//   hem    [0,        3200000)   N*64 ushort (bf16 h_em)
//   s8     [3200000,  4000000)   N*8 f32  [s_src+att_b (4) | s_dst (4)]
//   Wct    [4000000,  4010560)   21120 ushort
//   off8   [4010560,  4010568)   8 f32
//   rowptr [4010568,  4110576)   N+1 ints (+pad)
//   cbase  [4110576,  4266976)   156400 ints (scanned bucket/block bases)
//   bsum   [4266976,  4267232)   256 ints
//   boff   [4267232,  4267488)   256 ints
//   pairs  [4267488,  7467488)   E ints (lsrc<<20 | dst, bucket-partitioned)
//   sdst   [7467488, 10667488)   E ints (dst sorted by src)
//   counts [7467488,  7623888)   156400 ints — OVERLAYS sdst (dead by bsort)
// total 42.67 MB (< 42.8 MB proven in R2)
// ---------------------------------------------------------------------------

typedef __attribute__((ext_vector_type(8))) short short8;
typedef __attribute__((ext_vector_type(4))) float f32x4;

__device__ __forceinline__ unsigned short f2bf(float f) {
    unsigned u = __float_as_uint(f);
    return (unsigned short)((u + 0x7FFFu + ((u >> 16) & 1u)) >> 16);  // RNE
}

__device__ __forceinline__ float rdlf(float v, int l) {
    return __int_as_float(__builtin_amdgcn_readlane(__float_as_int(v), l));
}

// One wave per k (64 blocks x 4 waves): coalesced loads + shuffle reduce.
__global__ __launch_bounds__(256) void fuse_weights_kernel(
    const float* __restrict__ W_lin, const float* __restrict__ b_lin,
    const float* __restrict__ att_w, const float* __restrict__ emb_w,
    unsigned short* __restrict__ Wct, float* __restrict__ off8) {
    const int wave = threadIdx.x >> 6, lane = threadIdx.x & 63;
    const int k = blockIdx.x * 4 + wave;  // 0..255
    float4 wv = *(const float4*)(W_lin + k * 256 + lane * 4);
    float acc[8];
#pragma unroll
    for (int j = 0; j < 8; ++j) {
        int l = j & 3, part = j >> 2;
        float4 av = *(const float4*)(att_w + l * 512 + part * 256 + lane * 4);
        acc[j] = wv.x * av.x + wv.y * av.y + wv.z * av.z + wv.w * av.w;
    }
#pragma unroll
    for (int j = 0; j < 8; ++j) {
        float v = acc[j];
#pragma unroll
        for (int off = 32; off >= 1; off >>= 1) v += __shfl_xor(v, off);
        acc[j] = v;
    }
    if (lane < 8) {  // static-index select (avoid scratch)
        float v = acc[0];
#pragma unroll
        for (int j = 1; j < 8; ++j) if (lane == j) v = acc[j];
        Wct[(64 + lane) * WCT_STRIDE + k] = f2bf(v);
    }
    Wct[lane * WCT_STRIDE + k] = f2bf(emb_w[k * 64 + lane]);  // emb transpose
    if (lane < 8) Wct[(72 + lane) * WCT_STRIDE + k] = 0;      // unused cols
    if (k < 8) {  // off8[k] = b_lin . a_row(k)
        int l = k & 3, part = k >> 2;
        float4 av = *(const float4*)(att_w + l * 512 + part * 256 + lane * 4);
        float4 bv = *(const float4*)(b_lin + lane * 4);
        float p = bv.x * av.x + bv.y * av.y + bv.z * av.z + bv.w * av.w;
#pragma unroll
        for (int off = 32; off >= 1; off >>= 1) p += __shfl_xor(p, off);
        if (lane == 0) off8[k] = p;
    }
}

// MFMA row kernel: one wave per 16-row tile, [hem | s8] = X @ Wct^T.
__global__ __launch_bounds__(256) void row_mfma_kernel(
    const float* __restrict__ x, const unsigned short* __restrict__ Wct,
    const float* __restrict__ off8, const float* __restrict__ att_b,
    const float* __restrict__ emb_b,
    unsigned short* __restrict__ hem, float* __restrict__ s8) {
    __shared__ unsigned short Wl[WCT_ELEMS];  // stride-264 (2-way, free)
    const int tid = threadIdx.x;
    for (int i = tid; i < WCT_ELEMS / 8; i += 256)
        ((uint4*)Wl)[i] = ((const uint4*)Wct)[i];
    __syncthreads();
    const int wave = tid >> 6, lane = tid & 63;
    const int tile = blockIdx.x * 4 + wave;  // 6250 tiles of 16 rows
    if (tile >= N_NODES / 16) return;
    const int row0 = tile * 16;
    const int r = lane & 15, g = lane >> 4;
    const float* xr = x + (size_t)(row0 + r) * 256 + g * 8;

    f32x4 acc[5];
#pragma unroll
    for (int n = 0; n < 5; ++n) acc[n] = (f32x4){0.f, 0.f, 0.f, 0.f};

    for (int kk = 0; kk < 8; ++kk) {
        float4 xa = *(const float4*)(xr + kk * 32);
        float4 xb = *(const float4*)(xr + kk * 32 + 4);
        short8 a;
        a[0] = (short)f2bf(xa.x); a[1] = (short)f2bf(xa.y);
        a[2] = (short)f2bf(xa.z); a[3] = (short)f2bf(xa.w);
        a[4] = (short)f2bf(xb.x); a[5] = (short)f2bf(xb.y);
        a[6] = (short)f2bf(xb.z); a[7] = (short)f2bf(xb.w);
        const int bk = kk * 32 + g * 8;
#pragma unroll
        for (int n = 0; n < 5; ++n) {
            short8 b = *(const short8*)(&Wl[(16 * n + r) * WCT_STRIDE + bk]);
            acc[n] = __builtin_amdgcn_mfma_f32_16x16x32_bf16(a, b, acc[n], 0, 0, 0);
        }
    }
#pragma unroll
    for (int q = 0; q < 4; ++q) {
        const int orow = row0 + g * 4 + q;
#pragma unroll
        for (int n = 0; n < 4; ++n)
            hem[(size_t)orow * 64 + 16 * n + r] =
                f2bf(acc[n][q] + emb_b[16 * n + r]);
        if (r < 8)
            s8[(size_t)orow * 8 + r] =
                acc[4][q] + off8[r] + (r < 4 ? att_b[r] : 0.f);
    }
}

// ---- stage 1: per-(block,bucket) counts via LDS histogram ----
__global__ __launch_bounds__(256) void bcount_kernel(const int* __restrict__ src,
                                                     int* __restrict__ counts) {
    __shared__ int h[NBUCKETS];
    for (int i = threadIdx.x; i < NBUCKETS; i += 256) h[i] = 0;
    __syncthreads();
    const int base = blockIdx.x * CHUNK1;
    for (int i = threadIdx.x; i < CHUNK1; i += 256)
        atomicAdd(&h[src[base + i] >> BSHIFT], 1);
    __syncthreads();
    for (int i = threadIdx.x; i < NBUCKETS; i += 256)
        counts[i * NB1 + blockIdx.x] = h[i];
}

// ---- generic 3-kernel exclusive scan over counts[SCAN_LEN] -> cbase ----
__global__ __launch_bounds__(256) void scan1_kernel(const int* __restrict__ counts,
                                                    int* __restrict__ bsum) {
    __shared__ int red[256];
    const int b = blockIdx.x, t = threadIdx.x;
    const int base = b * SCAN_CHUNK;
    int s = 0;
    for (int i = t; i < SCAN_CHUNK; i += 256) {
        int idx = base + i;
        s += (idx < SCAN_LEN) ? counts[idx] : 0;
    }
    red[t] = s;
    __syncthreads();
    for (int off = 128; off >= 1; off >>= 1) {
        if (t < off) red[t] += red[t + off];
        __syncthreads();
    }
    if (t == 0) bsum[b] = red[0];
}

__global__ __launch_bounds__(256) void scan2_kernel(const int* __restrict__ bsum,
                                                    int* __restrict__ boff) {
    __shared__ int sh[256];
    const int t = threadIdx.x;
    sh[t] = (t < SCAN_BLOCKS) ? bsum[t] : 0;
    __syncthreads();
    for (int off = 1; off < 256; off <<= 1) {
        int v = (t >= off) ? sh[t - off] : 0;
        __syncthreads();
        sh[t] += v;
        __syncthreads();
    }
    if (t < SCAN_BLOCKS) boff[t] = (t == 0) ? 0 : sh[t - 1];
}

__global__ __launch_bounds__(256) void scan3_kernel(const int* __restrict__ counts,
                                                    const int* __restrict__ boff,
                                                    int* __restrict__ cbase) {
    __shared__ int sh[256];
    const int b = blockIdx.x, t = threadIdx.x;
    const int base = b * SCAN_CHUNK;
    int running = boff[b];
    for (int tile = 0; tile < SCAN_CHUNK; tile += 256) {
        const int idx = base + tile + t;
        const int v = (idx < SCAN_LEN) ? counts[idx] : 0;
        sh[t] = v;
        __syncthreads();
        for (int off = 1; off < 256; off <<= 1) {
            int u = (t >= off) ? sh[t - off] : 0;
            __syncthreads();
            sh[t] += u;
            __syncthreads();
        }
        if (idx < SCAN_LEN) cbase[idx] = running + sh[t] - v;
        running += sh[255];
        __syncthreads();
    }
}

// ---- stage 2: partition edges into bucket-contiguous regions ----
__global__ __launch_bounds__(256) void bpart_kernel(const int* __restrict__ src,
                                                    const int* __restrict__ dst,
                                                    const int* __restrict__ cbase,
                                                    int* __restrict__ pairs) {
    __shared__ int cur[NBUCKETS];
    for (int i = threadIdx.x; i < NBUCKETS; i += 256)
        cur[i] = cbase[i * NB1 + blockIdx.x];
    __syncthreads();
    const int base = blockIdx.x * CHUNK1;
    for (int i = threadIdx.x; i < CHUNK1; i += 256) {
        int s = src[base + i];
        int pos = atomicAdd(&cur[s >> BSHIFT], 1);
        pairs[pos] = ((s & (BWIDTH - 1)) << 20) | dst[base + i];
    }
}

// ---- stage 3: per-bucket counting sort; emits rowptr + sorted dst ----
__global__ __launch_bounds__(256) void bsort_kernel(const int* __restrict__ cbase,
                                                    const int* __restrict__ pairs,
                                                    int* __restrict__ sdst,
                                                    int* __restrict__ rowptr) {
    __shared__ int h[BWIDTH];
    const int b = blockIdx.x, t = threadIdx.x;
    const int beg = cbase[b * NB1];
    const int end = (b == NBUCKETS - 1) ? E_EDGES : cbase[(b + 1) * NB1];
    if (t < BWIDTH) h[t] = 0;
    __syncthreads();
    for (int i = beg + t; i < end; i += 256)
        atomicAdd(&h[pairs[i] >> 20], 1);
    __syncthreads();
    if (t == 0) {  // serial exclusive scan of 128 (cheap)
        int run = 0;
        for (int i = 0; i < BWIDTH; ++i) { int c = h[i]; h[i] = run; run += c; }
    }
    __syncthreads();
    const int s0 = b << BSHIFT;
    if (t < BWIDTH && s0 + t < N_NODES) rowptr[s0 + t] = beg + h[t];
    if (b == NBUCKETS - 1 && t == 0) rowptr[N_NODES] = E_EDGES;
    __syncthreads();  // rowptr reads h before placement mutates it
    for (int i = beg + t; i < end; i += 256) {
        int p = pairs[i];
        int pos = beg + atomicAdd(&h[p >> 20], 1);
        sdst[pos] = p & 0xFFFFF;
    }
}

// One wave per src node; readlane broadcast, bf16 hem gather.
__global__ __launch_bounds__(256) void node_kernel(
    const int* __restrict__ rowptr, const int* __restrict__ sdst,
    const float* __restrict__ s8, const unsigned short* __restrict__ hem,
    float* __restrict__ out) {
    const int lane = threadIdx.x & 63;
    const int gw = (blockIdx.x * blockDim.x + threadIdx.x) >> 6;
    const int nw = (gridDim.x * blockDim.x) >> 6;
    for (int s = gw; s < N_NODES; s += nw) {
        const int beg = rowptr[s], end = rowptr[s + 1];
        const float4 ssv = *(const float4*)(s8 + (size_t)s * 8);  // +att_b
        float a0 = 0.f, a1 = 0.f, a2 = 0.f, a3 = 0.f;
        float d0 = 0.f, d1 = 0.f, d2 = 0.f, d3 = 0.f;
        for (int base = beg; base < end; base += 64) {
            const int m = min(64, end - base);
            int dj = 0;
            float w0 = 0.f, w1 = 0.f, w2 = 0.f, w3 = 0.f;
            if (lane < m) {
                dj = sdst[base + lane];
                float4 sd = *(const float4*)(s8 + (size_t)dj * 8 + 4);
                w0 = __expf(1.f / (1.f + __expf(-(ssv.x + sd.x))));
                w1 = __expf(1.f / (1.f + __expf(-(ssv.y + sd.y))));
                w2 = __expf(1.f / (1.f + __expf(-(ssv.z + sd.z))));
                w3 = __expf(1.f / (1.f + __expf(-(ssv.w + sd.w))));
            }
            int j = 0;
            for (; j + 1 < m; j += 2) {
                const int ra = __builtin_amdgcn_readlane(dj, j);
                const int rb = __builtin_amdgcn_readlane(dj, j + 1);
                const float va0 = rdlf(w0, j), va1 = rdlf(w1, j);
                const float va2 = rdlf(w2, j), va3 = rdlf(w3, j);
                const float vb0 = rdlf(w0, j + 1), vb1 = rdlf(w1, j + 1);
                const float vb2 = rdlf(w2, j + 1), vb3 = rdlf(w3, j + 1);
                const float ha = __uint_as_float(
                    (unsigned)hem[(size_t)ra * 64 + lane] << 16);
                const float hb = __uint_as_float(
                    (unsigned)hem[(size_t)rb * 64 + lane] << 16);
                a0 += va0 * ha; a1 += va1 * ha; a2 += va2 * ha; a3 += va3 * ha;
                d0 += va0 + vb0; d1 += va1 + vb1;
                d2 += va2 + vb2; d3 += va3 + vb3;
                a0 += vb0 * hb; a1 += vb1 * hb; a2 += vb2 * hb; a3 += vb3 * hb;
            }
            if (j < m) {
                const int ra = __builtin_amdgcn_readlane(dj, j);
                const float v0 = rdlf(w0, j), v1 = rdlf(w1, j);
                const float v2 = rdlf(w2, j), v3 = rdlf(w3, j);
                const float ha = __uint_as_float(
                    (unsigned)hem[(size_t)ra * 64 + lane] << 16);
                a0 += v0 * ha; a1 += v1 * ha; a2 += v2 * ha; a3 += v3 * ha;
                d0 += v0; d1 += v1; d2 += v2; d3 += v3;
            }
        }
        float* o = out + (size_t)s * 256;
        o[lane]       = d0 > 0.f ? a0 / d0 : 0.f;
        o[64 + lane]  = d1 > 0.f ? a1 / d1 : 0.f;
        o[128 + lane] = d2 > 0.f ? a2 / d2 : 0.f;
        o[192 + lane] = d3 > 0.f ? a3 / d3 : 0.f;
    }
}

extern "C" void kernel_launch(void* const* d_in, const int* in_sizes, int n_in,
                              void* d_out, int out_size, void* d_ws, size_t ws_size,
                              hipStream_t stream) {
    const float* x     = (const float*)d_in[0];
    const int*   src   = (const int*)d_in[1];
    const int*   dst   = (const int*)d_in[2];
    const float* W_lin = (const float*)d_in[3];
    const float* b_lin = (const float*)d_in[4];
    const float* att_w = (const float*)d_in[5];
    const float* att_b = (const float*)d_in[6];
    const float* emb_w = (const float*)d_in[7];
    const float* emb_b = (const float*)d_in[8];
    float* out = (float*)d_out;
    float* ws  = (float*)d_ws;

    unsigned short* hem = (unsigned short*)ws;
    float* s8     = ws + 3200000;
    unsigned short* Wct = (unsigned short*)(ws + 4000000);
    float* off8   = ws + 4010560;
    int*   rowptr = (int*)(ws + 4010568);
    int*   cbase  = (int*)(ws + 4110576);
    int*   bsum   = (int*)(ws + 4266976);
    int*   boff   = (int*)(ws + 4267232);
    int*   pairs  = (int*)(ws + 4267488);
    int*   sdst   = (int*)(ws + 7467488);
    int*   counts = (int*)(ws + 7467488);  // overlays sdst (dead by bsort)

    fuse_weights_kernel<<<64, 256, 0, stream>>>(W_lin, b_lin, att_w, emb_w,
                                                Wct, off8);
    row_mfma_kernel<<<1563, 256, 0, stream>>>(x, Wct, off8, att_b, emb_b,
                                              hem, s8);
    bcount_kernel<<<NB1, 256, 0, stream>>>(src, counts);
    scan1_kernel<<<SCAN_BLOCKS, 256, 0, stream>>>(counts, bsum);
    scan2_kernel<<<1, 256, 0, stream>>>(bsum, boff);
    scan3_kernel<<<SCAN_BLOCKS, 256, 0, stream>>>(counts, boff, cbase);
    bpart_kernel<<<NB1, 256, 0, stream>>>(src, dst, cbase, pairs);
    bsort_kernel<<<NBUCKETS, 256, 0, stream>>>(cbase, pairs, sdst, rowptr);
    node_kernel<<<4096, 256, 0, stream>>>(rowptr, sdst, s8, hem, out);
}

// Round 8
// 287.113 us; speedup vs baseline: 2.8621x; 1.1131x over previous
//
#include <hip/hip_runtime.h>

#define N_NODES 100000
#define E_EDGES 3200000

// ---- bucket sort geometry ----
#define BSHIFT 7
#define BWIDTH 128                       // src values per bucket
#define NBUCKETS 782                     // ceil(100000/128)
#define NB1 200                          // partition blocks
#define CHUNK1 16000                     // NB1*CHUNK1 == E_EDGES exactly
#define SCAN_LEN (NBUCKETS * NB1)        // 156400
#define SCAN_CHUNK 1024
#define SCAN_BLOCKS 153                  // ceil(156400/1024)

// Wct: transposed fused weight matrix, bf16, [80 cols][264 k-stride]
#define WCT_STRIDE 264
#define WCT_ELEMS (80 * WCT_STRIDE)      // 21120 ushorts

// ---------------------------------------------------------------------------
// ws layout (int/float offsets):
//   hem    [0,        3200000)   N*64 ushort (bf16 h_em)
//   s8     [3200000,  4000000)   N*8 f32  [s_src+att_b (4) | s_dst (4)]
//   Wct    [4000000,  4010560)   21120 ushort
//   off8   [4010560,  4010568)   8 f32
//   rowptr [4010568,  4110576)   N+1 ints (+pad)
//   cbase  [4110576,  4266976)   156400 ints (scanned bucket/block bases)
//   bsum   [4266976,  4267232)   256 ints
//   boff   [4267232,  4267488)   256 ints
//   pairs  [4267488,  7467488)   E ints (lsrc<<20 | dst, bucket-partitioned)
//   sdst   [7467488, 10667488)   E ints (dst sorted by src)
//   counts [7467488,  7623888)   156400 ints — OVERLAYS sdst (dead by bsort)
// ---------------------------------------------------------------------------

typedef __attribute__((ext_vector_type(8))) short short8;
typedef __attribute__((ext_vector_type(4))) float f32x4;

__device__ __forceinline__ unsigned short f2bf(float f) {
    unsigned u = __float_as_uint(f);
    return (unsigned short)((u + 0x7FFFu + ((u >> 16) & 1u)) >> 16);  // RNE
}

__device__ __forceinline__ float rdlf(float v, int l) {
    return __int_as_float(__builtin_amdgcn_readlane(__float_as_int(v), l));
}

// One wave per k (64 blocks x 4 waves): coalesced loads + shuffle reduce.
__global__ __launch_bounds__(256) void fuse_weights_kernel(
    const float* __restrict__ W_lin, const float* __restrict__ b_lin,
    const float* __restrict__ att_w, const float* __restrict__ emb_w,
    unsigned short* __restrict__ Wct, float* __restrict__ off8) {
    const int wave = threadIdx.x >> 6, lane = threadIdx.x & 63;
    const int k = blockIdx.x * 4 + wave;  // 0..255
    float4 wv = *(const float4*)(W_lin + k * 256 + lane * 4);
    float acc[8];
#pragma unroll
    for (int j = 0; j < 8; ++j) {
        int l = j & 3, part = j >> 2;
        float4 av = *(const float4*)(att_w + l * 512 + part * 256 + lane * 4);
        acc[j] = wv.x * av.x + wv.y * av.y + wv.z * av.z + wv.w * av.w;
    }
#pragma unroll
    for (int j = 0; j < 8; ++j) {
        float v = acc[j];
#pragma unroll
        for (int off = 32; off >= 1; off >>= 1) v += __shfl_xor(v, off);
        acc[j] = v;
    }
    if (lane < 8) {  // static-index select (avoid scratch)
        float v = acc[0];
#pragma unroll
        for (int j = 1; j < 8; ++j) if (lane == j) v = acc[j];
        Wct[(64 + lane) * WCT_STRIDE + k] = f2bf(v);
    }
    Wct[lane * WCT_STRIDE + k] = f2bf(emb_w[k * 64 + lane]);  // emb transpose
    if (lane < 8) Wct[(72 + lane) * WCT_STRIDE + k] = 0;      // unused cols
    if (k < 8) {  // off8[k] = b_lin . a_row(k)
        int l = k & 3, part = k >> 2;
        float4 av = *(const float4*)(att_w + l * 512 + part * 256 + lane * 4);
        float4 bv = *(const float4*)(b_lin + lane * 4);
        float p = bv.x * av.x + bv.y * av.y + bv.z * av.z + bv.w * av.w;
#pragma unroll
        for (int off = 32; off >= 1; off >>= 1) p += __shfl_xor(p, off);
        if (lane == 0) off8[k] = p;
    }
}

// MFMA row kernel: one wave per 16-row tile, [hem | s8] = X @ Wct^T.
__global__ __launch_bounds__(256) void row_mfma_kernel(
    const float* __restrict__ x, const unsigned short* __restrict__ Wct,
    const float* __restrict__ off8, const float* __restrict__ att_b,
    const float* __restrict__ emb_b,
    unsigned short* __restrict__ hem, float* __restrict__ s8) {
    __shared__ unsigned short Wl[WCT_ELEMS];  // stride-264 (2-way, free)
    const int tid = threadIdx.x;
    for (int i = tid; i < WCT_ELEMS / 8; i += 256)
        ((uint4*)Wl)[i] = ((const uint4*)Wct)[i];
    __syncthreads();
    const int wave = tid >> 6, lane = tid & 63;
    const int tile = blockIdx.x * 4 + wave;  // 6250 tiles of 16 rows
    if (tile >= N_NODES / 16) return;
    const int row0 = tile * 16;
    const int r = lane & 15, g = lane >> 4;
    const float* xr = x + (size_t)(row0 + r) * 256 + g * 8;

    f32x4 acc[5];
#pragma unroll
    for (int n = 0; n < 5; ++n) acc[n] = (f32x4){0.f, 0.f, 0.f, 0.f};

    for (int kk = 0; kk < 8; ++kk) {
        float4 xa = *(const float4*)(xr + kk * 32);
        float4 xb = *(const float4*)(xr + kk * 32 + 4);
        short8 a;
        a[0] = (short)f2bf(xa.x); a[1] = (short)f2bf(xa.y);
        a[2] = (short)f2bf(xa.z); a[3] = (short)f2bf(xa.w);
        a[4] = (short)f2bf(xb.x); a[5] = (short)f2bf(xb.y);
        a[6] = (short)f2bf(xb.z); a[7] = (short)f2bf(xb.w);
        const int bk = kk * 32 + g * 8;
#pragma unroll
        for (int n = 0; n < 5; ++n) {
            short8 b = *(const short8*)(&Wl[(16 * n + r) * WCT_STRIDE + bk]);
            acc[n] = __builtin_amdgcn_mfma_f32_16x16x32_bf16(a, b, acc[n], 0, 0, 0);
        }
    }
#pragma unroll
    for (int q = 0; q < 4; ++q) {
        const int orow = row0 + g * 4 + q;
#pragma unroll
        for (int n = 0; n < 4; ++n)
            hem[(size_t)orow * 64 + 16 * n + r] =
                f2bf(acc[n][q] + emb_b[16 * n + r]);
        if (r < 8)
            s8[(size_t)orow * 8 + r] =
                acc[4][q] + off8[r] + (r < 4 ? att_b[r] : 0.f);
    }
}

// ---- stage 1: per-(block,bucket) counts via LDS histogram ----
__global__ __launch_bounds__(256) void bcount_kernel(const int* __restrict__ src,
                                                     int* __restrict__ counts) {
    __shared__ int h[NBUCKETS];
    for (int i = threadIdx.x; i < NBUCKETS; i += 256) h[i] = 0;
    __syncthreads();
    const int base = blockIdx.x * CHUNK1;
    for (int i = threadIdx.x; i < CHUNK1; i += 256)
        atomicAdd(&h[src[base + i] >> BSHIFT], 1);
    __syncthreads();
    for (int i = threadIdx.x; i < NBUCKETS; i += 256)
        counts[i * NB1 + blockIdx.x] = h[i];
}

// ---- generic 3-kernel exclusive scan over counts[SCAN_LEN] -> cbase ----
__global__ __launch_bounds__(256) void scan1_kernel(const int* __restrict__ counts,
                                                    int* __restrict__ bsum) {
    __shared__ int red[256];
    const int b = blockIdx.x, t = threadIdx.x;
    const int base = b * SCAN_CHUNK;
    int s = 0;
    for (int i = t; i < SCAN_CHUNK; i += 256) {
        int idx = base + i;
        s += (idx < SCAN_LEN) ? counts[idx] : 0;
    }
    red[t] = s;
    __syncthreads();
    for (int off = 128; off >= 1; off >>= 1) {
        if (t < off) red[t] += red[t + off];
        __syncthreads();
    }
    if (t == 0) bsum[b] = red[0];
}

__global__ __launch_bounds__(256) void scan2_kernel(const int* __restrict__ bsum,
                                                    int* __restrict__ boff) {
    __shared__ int sh[256];
    const int t = threadIdx.x;
    sh[t] = (t < SCAN_BLOCKS) ? bsum[t] : 0;
    __syncthreads();
    for (int off = 1; off < 256; off <<= 1) {
        int v = (t >= off) ? sh[t - off] : 0;
        __syncthreads();
        sh[t] += v;
        __syncthreads();
    }
    if (t < SCAN_BLOCKS) boff[t] = (t == 0) ? 0 : sh[t - 1];
}

__global__ __launch_bounds__(256) void scan3_kernel(const int* __restrict__ counts,
                                                    const int* __restrict__ boff,
                                                    int* __restrict__ cbase) {
    __shared__ int sh[256];
    const int b = blockIdx.x, t = threadIdx.x;
    const int base = b * SCAN_CHUNK;
    int running = boff[b];
    for (int tile = 0; tile < SCAN_CHUNK; tile += 256) {
        const int idx = base + tile + t;
        const int v = (idx < SCAN_LEN) ? counts[idx] : 0;
        sh[t] = v;
        __syncthreads();
        for (int off = 1; off < 256; off <<= 1) {
            int u = (t >= off) ? sh[t - off] : 0;
            __syncthreads();
            sh[t] += u;
            __syncthreads();
        }
        if (idx < SCAN_LEN) cbase[idx] = running + sh[t] - v;
        running += sh[255];
        __syncthreads();
    }
}

// ---- stage 2: partition edges into bucket-contiguous regions ----
__global__ __launch_bounds__(256) void bpart_kernel(const int* __restrict__ src,
                                                    const int* __restrict__ dst,
                                                    const int* __restrict__ cbase,
                                                    int* __restrict__ pairs) {
    __shared__ int cur[NBUCKETS];
    for (int i = threadIdx.x; i < NBUCKETS; i += 256)
        cur[i] = cbase[i * NB1 + blockIdx.x];
    __syncthreads();
    const int base = blockIdx.x * CHUNK1;
    for (int i = threadIdx.x; i < CHUNK1; i += 256) {
        int s = src[base + i];
        int pos = atomicAdd(&cur[s >> BSHIFT], 1);
        pairs[pos] = ((s & (BWIDTH - 1)) << 20) | dst[base + i];
    }
}

// ---- stage 3: per-bucket counting sort; emits rowptr + sorted dst ----
__global__ __launch_bounds__(256) void bsort_kernel(const int* __restrict__ cbase,
                                                    const int* __restrict__ pairs,
                                                    int* __restrict__ sdst,
                                                    int* __restrict__ rowptr) {
    __shared__ int h[BWIDTH];
    const int b = blockIdx.x, t = threadIdx.x;
    const int beg = cbase[b * NB1];
    const int end = (b == NBUCKETS - 1) ? E_EDGES : cbase[(b + 1) * NB1];
    if (t < BWIDTH) h[t] = 0;
    __syncthreads();
    for (int i = beg + t; i < end; i += 256)
        atomicAdd(&h[pairs[i] >> 20], 1);
    __syncthreads();
    if (t == 0) {  // serial exclusive scan of 128 (cheap)
        int run = 0;
        for (int i = 0; i < BWIDTH; ++i) { int c = h[i]; h[i] = run; run += c; }
    }
    __syncthreads();
    const int s0 = b << BSHIFT;
    if (t < BWIDTH && s0 + t < N_NODES) rowptr[s0 + t] = beg + h[t];
    if (b == NBUCKETS - 1 && t == 0) rowptr[N_NODES] = E_EDGES;
    __syncthreads();  // rowptr reads h before placement mutates it
    for (int i = beg + t; i < end; i += 256) {
        int p = pairs[i];
        int pos = beg + atomicAdd(&h[p >> 20], 1);
        sdst[pos] = p & 0xFFFFF;
    }
}

// MFMA node kernel: one wave per src node. out[4 heads][64 cols] = W @ Hem
// with K = edges. Frag conventions identical to row_mfma (HW-verified):
//   A: row=lane&15, k=(lane>>4)*8+elem;  B: col=lane&15, same k-map;
//   C/D: col=lane&15, row=(lane>>4)*4+reg.
// k<->edge bijection: edge = j*4 + g  (g=lane>>4, j=elem) so a ragged tail of
// m edges costs ceil(m/4) j-iterations. A rows 4..15 and invalid edges get
// w=0 (zeroed a-frag masks any garbage in b). Denominator = sum of the SAME
// truncated-bf16 weights used in the numerator (rounding cancels in ratio),
// accumulated per-lane and reduced with 2 shfl_xor over the g bits.
__global__ __launch_bounds__(256) void node_mfma_kernel(
    const int* __restrict__ rowptr, const int* __restrict__ sdst,
    const float* __restrict__ s8, const unsigned short* __restrict__ hem,
    float* __restrict__ out) {
    const int lane = threadIdx.x & 63;
    const int r = lane & 15, g = lane >> 4;
    const int r3 = r & 3;
    const bool headlane = (r < 4);
    const int gw = (blockIdx.x * blockDim.x + threadIdx.x) >> 6;
    const int nw = (gridDim.x * blockDim.x) >> 6;
    for (int s = gw; s < N_NODES; s += nw) {
        const int beg = rowptr[s], end = rowptr[s + 1];
        const float ssr = s8[(size_t)s * 8 + r3];  // s_src head r3 (+att_b)
        f32x4 acc0 = {0.f, 0.f, 0.f, 0.f}, acc1 = {0.f, 0.f, 0.f, 0.f};
        f32x4 acc2 = {0.f, 0.f, 0.f, 0.f}, acc3 = {0.f, 0.f, 0.f, 0.f};
        float dsum = 0.f;
        for (int base = beg; base < end; base += 32) {
            const int m = end - base;  // remaining edges (>=1)
            short8 a  = {0, 0, 0, 0, 0, 0, 0, 0};
            short8 b0 = {0, 0, 0, 0, 0, 0, 0, 0};
            short8 b1 = {0, 0, 0, 0, 0, 0, 0, 0};
            short8 b2 = {0, 0, 0, 0, 0, 0, 0, 0};
            short8 b3 = {0, 0, 0, 0, 0, 0, 0, 0};
#pragma unroll
            for (int j = 0; j < 8; ++j) {
                if (4 * j < m) {  // wave-uniform -> scalar skip
                    const int e = base + 4 * j + g;
                    const bool valid = (e < end);
                    const int ee = valid ? e : beg;
                    const int dj = sdst[ee];
                    // weight chain (meaningful for head lanes only)
                    const float sd = s8[(size_t)dj * 8 + 4 + r3];
                    const float t = ssr + sd;
                    const float sg = 1.f / (1.f + __expf(-t));
                    float w = __expf(sg);
                    w = (valid && headlane) ? w : 0.f;
                    const unsigned ub = __float_as_uint(w) & 0xFFFF0000u;
                    a[j] = (short)(ub >> 16);          // truncated bf16
                    dsum += __uint_as_float(ub);       // same value as used
                    // b-frags: hem[dj][16n + c], c == r
                    const unsigned short* hrow = hem + (size_t)dj * 64 + r;
                    b0[j] = (short)hrow[0];
                    b1[j] = (short)hrow[16];
                    b2[j] = (short)hrow[32];
                    b3[j] = (short)hrow[48];
                }
            }
            acc0 = __builtin_amdgcn_mfma_f32_16x16x32_bf16(a, b0, acc0, 0, 0, 0);
            acc1 = __builtin_amdgcn_mfma_f32_16x16x32_bf16(a, b1, acc1, 0, 0, 0);
            acc2 = __builtin_amdgcn_mfma_f32_16x16x32_bf16(a, b2, acc2, 0, 0, 0);
            acc3 = __builtin_amdgcn_mfma_f32_16x16x32_bf16(a, b3, acc3, 0, 0, 0);
        }
        // reduce dsum over the two g bits -> every lane holds d_{its r}
        dsum += __shfl_xor(dsum, 16);
        dsum += __shfl_xor(dsum, 32);
        const float d0 = rdlf(dsum, 0), d1 = rdlf(dsum, 1);
        const float d2 = rdlf(dsum, 2), d3 = rdlf(dsum, 3);
        const float i0 = d0 > 0.f ? 1.f / d0 : 0.f;
        const float i1 = d1 > 0.f ? 1.f / d1 : 0.f;
        const float i2 = d2 > 0.f ? 1.f / d2 : 0.f;
        const float i3 = d3 > 0.f ? 1.f / d3 : 0.f;
        if (g == 0) {  // lanes 0..15 hold head rows 0..3 (reg q)
            float* o = out + (size_t)s * 256 + r;
#pragma unroll
            for (int n = 0; n < 4; ++n) {
                o[0 * 64 + n * 16] = acc0[0] * i0, o[1 * 64 + n * 16] = acc0[1] * i1,
                o[2 * 64 + n * 16] = acc0[2] * i2, o[3 * 64 + n * 16] = acc0[3] * i3;
                // advance to next n-tile's accumulator via rotation below
                f32x4 tmp = acc0; acc0 = acc1; acc1 = acc2; acc2 = acc3; acc3 = tmp;
            }
        }
    }
}

extern "C" void kernel_launch(void* const* d_in, const int* in_sizes, int n_in,
                              void* d_out, int out_size, void* d_ws, size_t ws_size,
                              hipStream_t stream) {
    const float* x     = (const float*)d_in[0];
    const int*   src   = (const int*)d_in[1];
    const int*   dst   = (const int*)d_in[2];
    const float* W_lin = (const float*)d_in[3];
    const float* b_lin = (const float*)d_in[4];
    const float* att_w = (const float*)d_in[5];
    const float* att_b = (const float*)d_in[6];
    const float* emb_w = (const float*)d_in[7];
    const float* emb_b = (const float*)d_in[8];
    float* out = (float*)d_out;
    float* ws  = (float*)d_ws;

    unsigned short* hem = (unsigned short*)ws;
    float* s8     = ws + 3200000;
    unsigned short* Wct = (unsigned short*)(ws + 4000000);
    float* off8   = ws + 4010560;
    int*   rowptr = (int*)(ws + 4010568);
    int*   cbase  = (int*)(ws + 4110576);
    int*   bsum   = (int*)(ws + 4266976);
    int*   boff   = (int*)(ws + 4267232);
    int*   pairs  = (int*)(ws + 4267488);
    int*   sdst   = (int*)(ws + 7467488);
    int*   counts = (int*)(ws + 7467488);  // overlays sdst (dead by bsort)

    fuse_weights_kernel<<<64, 256, 0, stream>>>(W_lin, b_lin, att_w, emb_w,
                                                Wct, off8);
    row_mfma_kernel<<<1563, 256, 0, stream>>>(x, Wct, off8, att_b, emb_b,
                                              hem, s8);
    bcount_kernel<<<NB1, 256, 0, stream>>>(src, counts);
    scan1_kernel<<<SCAN_BLOCKS, 256, 0, stream>>>(counts, bsum);
    scan2_kernel<<<1, 256, 0, stream>>>(bsum, boff);
    scan3_kernel<<<SCAN_BLOCKS, 256, 0, stream>>>(counts, boff, cbase);
    bpart_kernel<<<NB1, 256, 0, stream>>>(src, dst, cbase, pairs);
    bsort_kernel<<<NBUCKETS, 256, 0, stream>>>(cbase, pairs, sdst, rowptr);
    node_mfma_kernel<<<4096, 256, 0, stream>>>(rowptr, sdst, s8, hem, out);
}